// Round 4
// baseline (2222.757 us; speedup 1.0000x reference)
//
#include <hip/hip_runtime.h>
#include <hip/hip_bf16.h>
#include <cstdint>

// ---------------------------------------------------------------------------
// Decoder LSTM (teacher-forced), MI355X.
//   1. cvt_bf16: W_out, W_ih, W_hh fp32 -> bf16 (ws)
//   2. gather_embed: X[t*16+b] = bf16(relu(emb[tok])) (t-major) + NaN-fill Hs
//   3. gemm_bt: G0 = X @ W_ih^T + b_ih + b_hh  (fp32, t-major rows)
//   4. lstm_rec: 16 blocks x 512 thr. W_hh slice in LDS (swizzled, 128KB).
//      h exchange is DATA-AS-FLAG: Hs pre-filled with bf16 NaN sentinel
//      (0x7FC0, unreachable since |h|<1); writers fire-and-forget 8B
//      agent-scope stores; readers batch-load 16 chunks coherently and
//      retry only stale ones. No flags, no fences, no store-ack in the
//      128-step loop. (R2: flag+ack+serialized loads = 11 us/step,
//      VGPR=60 showed W got evicted by per-iteration memory clobbers.)
//   5. gemm_bt (tmajor epilogue): logits = Hs @ W_out^T + b_out -> d_out
// ---------------------------------------------------------------------------

#define V_ 32000
#define H_ 512
#define B_ 16
#define T_ 128

typedef __attribute__((ext_vector_type(8))) short s16x8;
typedef __attribute__((ext_vector_type(4))) float f32x4;

typedef unsigned int __attribute__((address_space(1))) as1_u32;
typedef unsigned int __attribute__((address_space(3))) as3_u32;

#define MFMA16 __builtin_amdgcn_mfma_f32_16x16x32_bf16

__device__ __forceinline__ void async_cp16(const void* g, void* l) {
  __builtin_amdgcn_global_load_lds((const as1_u32*)g, (as3_u32*)l, 16, 0, 0);
}

__device__ __forceinline__ short f2bf(float f) {
  union { float f; unsigned u; } v; v.f = f;
  unsigned r = v.u + 0x7fffu + ((v.u >> 16) & 1u);   // RNE, inputs finite
  return (short)(r >> 16);
}

// 16B coherent load: two relaxed agent-scope atomic 64-bit loads (bypass
// stale L1/L2, served at the IF coherence point).
__device__ __forceinline__ s16x8 load_h16(const short* p) {
  unsigned long long* q = (unsigned long long*)(void*)p;
  unsigned long long lo = __hip_atomic_load(q, __ATOMIC_RELAXED, __HIP_MEMORY_SCOPE_AGENT);
  unsigned long long hi = __hip_atomic_load(q + 1, __ATOMIC_RELAXED, __HIP_MEMORY_SCOPE_AGENT);
  union { unsigned long long u[2]; s16x8 v; } r;
  r.u[0] = lo; r.u[1] = hi;
  return r.v;
}

// ---------------------------------------------------------------------------
__global__ void cvt_bf16(const float* __restrict__ in, short* __restrict__ out, int n4) {
  int i = blockIdx.x * blockDim.x + threadIdx.x;
  if (i >= n4) return;
  float4 v = ((const float4*)in)[i];
  short4 o;
  o.x = f2bf(v.x); o.y = f2bf(v.y); o.z = f2bf(v.z); o.w = f2bf(v.w);
  ((short4*)out)[i] = o;
}

// grid 2048 blocks (one per (b,t)), 128 threads. X stored T-MAJOR: row t*16+b.
// Also NaN-fills Hs row m (sentinel for lstm_rec's data-spin), agent-scope
// stores so the fill never populates any L2 with soon-stale lines.
__global__ void gather_embed(const float* __restrict__ emb, const int* __restrict__ tgt,
                             short* __restrict__ X, short* __restrict__ Hs) {
  int m = blockIdx.x;
  int b = m >> 7, t = m & 127;
  int tok = (t == 0) ? 1 : tgt[b * T_ + t - 1];       // BOS = 1
  int k = threadIdx.x * 4;
  float4 v = *(const float4*)&emb[(size_t)tok * H_ + k];
  short4 o;
  o.x = f2bf(fmaxf(v.x, 0.f)); o.y = f2bf(fmaxf(v.y, 0.f));
  o.z = f2bf(fmaxf(v.z, 0.f)); o.w = f2bf(fmaxf(v.w, 0.f));
  *(short4*)&X[((size_t)t * 16 + b) * H_ + k] = o;
  __hip_atomic_store((unsigned long long*)&Hs[(size_t)m * H_ + threadIdx.x * 4],
                     0x7FC07FC07FC07FC0ull, __ATOMIC_RELAXED, __HIP_MEMORY_SCOPE_AGENT);
}

// ---------------------------------------------------------------------------
// C = A(MxK bf16) @ B(NxK bf16)^T + bias ; 128x128 tile, BK=64, 4 waves,
// XOR-swizzled LDS chunks -> conflict-free ds_read_b128.
// tmajor: A rows are t*16+b, output rows must be b*T+t (logits GEMM).
__global__ __launch_bounds__(256, 2) void gemm_bt(
    const short* __restrict__ A, const short* __restrict__ B,
    const float* __restrict__ bias0, const float* __restrict__ bias1,
    float* __restrict__ out, int M, int N, int K, int ldo, int tmajor)
{
  __shared__ short As[1024 * 8];
  __shared__ short Bs[1024 * 8];
  const int tid = threadIdx.x;
  const int wave = tid >> 6, lane = tid & 63;
  const int row0 = blockIdx.y * 128, col0 = blockIdx.x * 128;
  const int m_in = lane & 15, quad = lane >> 4;
  const int wm = (wave >> 1) * 64, wn = (wave & 1) * 64;
  f32x4 acc[4][4] = {};
  for (int kt = 0; kt < K; kt += 64) {
    for (int i = 0; i < 4; ++i) {
      int s = (i * 4 + wave) * 64 + lane;
      int r = s >> 3, cs = s & 7, cd = cs ^ (r & 7);
      async_cp16(A + ((size_t)(row0 + r) * K + kt + cd * 8), &As[s * 8]);
      async_cp16(B + ((size_t)(col0 + r) * K + kt + cd * 8), &Bs[s * 8]);
    }
    __syncthreads();
    for (int kk = 0; kk < 2; ++kk) {
      s16x8 af[4], bfr[4];
      int c = kk * 4 + quad;
      for (int i = 0; i < 4; ++i) {
        int ra = wm + i * 16 + m_in;
        af[i] = *(const s16x8*)&As[(ra * 8 + (c ^ (ra & 7))) * 8];
        int rb = wn + i * 16 + m_in;
        bfr[i] = *(const s16x8*)&Bs[(rb * 8 + (c ^ (rb & 7))) * 8];
      }
      for (int i = 0; i < 4; ++i)
        for (int j = 0; j < 4; ++j)
          acc[i][j] = MFMA16(af[i], bfr[j], acc[i][j], 0, 0, 0);
    }
    __syncthreads();
  }
  for (int j = 0; j < 4; ++j) {
    int n = col0 + wn + j * 16 + m_in;
    float bs = bias0[n] + (bias1 ? bias1[n] : 0.f);
    for (int i = 0; i < 4; ++i) {
      int mrow = row0 + wm + i * 16 + quad * 4;      // D: col=lane&15, row=quad*4+reg
      f32x4 a = acc[i][j];
      for (int p = 0; p < 4; ++p) {
        int mr = mrow + p;
        int orow = tmajor ? ((mr & 15) * T_ + (mr >> 4)) : mr;
        out[(size_t)orow * ldo + n] = a[p] + bs;
      }
    }
  }
}

// ---------------------------------------------------------------------------
// Recurrence: 16 blocks x 512 threads (8 waves). Block S owns hidden slice
// [S*32, S*32+32); wave w owns units S*32+w*4..+4 for ALL 4 gates.
// W_hh slice resident in LDS (swizzled). Per step:
//   batch-load 16 h chunks (coherent) -> sentinel-spin on stale chunks ->
//   2 MFMA chains (B from LDS) -> in-wave LDS gate exchange -> fp32 gate
//   math -> pack h -> 8B agent store (fire-and-forget) -> G0 prefetch.
__global__ __launch_bounds__(512, 1) void lstm_rec(
    const float* __restrict__ G0,    // [2048][2048] fp32, rows t-major
    const short* __restrict__ Whh,   // [2048][512] bf16
    const float* __restrict__ h0, const float* __restrict__ c0,
    short* __restrict__ Hs,          // [2048][512] bf16, rows t-major, NaN-filled
    float* __restrict__ hcf)         // hf[B*H] then cf[B*H]
{
  __shared__ short Wl[8192 * 8];     // 128 rows x 64 chunks x 16B = 128KB
  __shared__ float gw_s[8 * 320];    // per-wave 16x20 fp32 scratch
  const int S = blockIdx.x;
  const int tid = threadIdx.x, wave = tid >> 6, lane = tid & 63;
  const int nin = lane & 15, quad = lane >> 4;
  const int g = nin >> 2, j = nin & 3;               // gate-major B-row mapping
  const int r = g * 32 + wave * 4 + j;               // local W row (B operand)

  // Stage W slice. Local row rr -> global unit (rr/32)*512 + S*32 + (rr%32).
  for (int i = tid; i < 8192; i += 512) {
    int rr = i >> 6, cs = i & 63, cd = cs ^ (rr & 7);
    int u = (rr >> 5) * 512 + S * 32 + (rr & 31);
    *(int4*)&Wl[i * 8] = *(const int4*)&Whh[(size_t)u * H_ + cd * 8];
  }
  const int goff = S * 32 + wave * 4 + quad;         // this lane's unit (reader view)
  float c_reg = c0[nin * 512 + goff];
  float* gw = gw_s + wave * 320;
  // G0 prefetch for tt=0 (row = 0*16 + nin)
  float gx0 = G0[(size_t)nin * 2048 + goff];
  float gx1 = G0[(size_t)nin * 2048 + 512 + goff];
  float gx2 = G0[(size_t)nin * 2048 + 1024 + goff];
  float gx3 = G0[(size_t)nin * 2048 + 1536 + goff];
  __syncthreads();                                   // Wl staged

  for (int tt = 0; tt < T_; ++tt) {
    // ---- acquire h(tt-1) into hv[16] ----
    s16x8 hv[16];
    if (tt == 0) {
#pragma unroll
      for (int ks = 0; ks < 16; ++ks) {
        const float* hp = h0 + nin * 512 + ks * 32 + quad * 8;
        float4 v0 = *(const float4*)hp, v1 = *(const float4*)(hp + 4);
        s16x8 af;
        af[0] = f2bf(v0.x); af[1] = f2bf(v0.y); af[2] = f2bf(v0.z); af[3] = f2bf(v0.w);
        af[4] = f2bf(v1.x); af[5] = f2bf(v1.y); af[6] = f2bf(v1.z); af[7] = f2bf(v1.w);
        hv[ks] = af;
      }
    } else {
      const short* hrow = Hs + ((size_t)(tt - 1) * 16 + nin) * 512 + quad * 8;
#pragma unroll
      for (int ks = 0; ks < 16; ++ks)
        hv[ks] = load_h16(hrow + ks * 32);           // batch-issued, pipelined
      while (true) {                                 // sentinel data-spin
        unsigned stale = 0;
#pragma unroll
        for (int ks = 0; ks < 16; ++ks)
          if (((unsigned short)hv[ks][0] == 0x7FC0u) ||
              ((unsigned short)hv[ks][4] == 0x7FC0u))
            stale |= 1u << ks;
        if (stale == 0) break;
        __builtin_amdgcn_s_sleep(1);
#pragma unroll
        for (int ks = 0; ks < 16; ++ks)
          if (stale & (1u << ks))
            hv[ks] = load_h16(hrow + ks * 32);
      }
    }
    // ---- MFMA: 16 batches x 16 (gate,unit) rows over K=512 ----
    f32x4 a0 = {}, a1 = {};
#pragma unroll
    for (int ks = 0; ks < 16; ++ks) {
      int c = ks * 4 + quad;
      s16x8 bw = *(const s16x8*)&Wl[(r * 64 + (c ^ (r & 7))) * 8];
      if (ks < 8) a0 = MFMA16(hv[ks], bw, a0, 0, 0, 0);
      else        a1 = MFMA16(hv[ks], bw, a1, 0, 0, 0);
    }
    f32x4 acc = a0 + a1;
    // in-wave gate exchange (no barrier; lgkmcnt orders ds ops per-wave)
    *(f32x4*)&gw[nin * 20 + quad * 4] = acc;         // [col=(g,j)][batch]
    float pi = gw[(0 * 4 + quad) * 20 + nin];
    float pf = gw[(1 * 4 + quad) * 20 + nin];
    float pg = gw[(2 * 4 + quad) * 20 + nin];
    float po = gw[(3 * 4 + quad) * 20 + nin];
    float xi = gx0 + pi, xf = gx1 + pf, xg = gx2 + pg, xo = gx3 + po;
    float si = 1.f / (1.f + __expf(-xi));
    float sf = 1.f / (1.f + __expf(-xf));
    float so = 1.f / (1.f + __expf(-xo));
    c_reg = sf * c_reg + si * tanhf(xg);
    float hn = so * tanhf(c_reg);
    // pack this wave's 4 units for batch nin, store 8B agent-scope
    int v0 = (int)(unsigned short)f2bf(hn);
    int v1 = __shfl(v0, (lane & 15) + 16);
    int v2 = __shfl(v0, (lane & 15) + 32);
    int v3 = __shfl(v0, (lane & 15) + 48);
    if (lane < 16) {
      unsigned long long pk = (unsigned long long)(unsigned)v0
                            | ((unsigned long long)(unsigned)v1 << 16)
                            | ((unsigned long long)(unsigned)v2 << 32)
                            | ((unsigned long long)(unsigned)v3 << 48);
      __hip_atomic_store(
          (unsigned long long*)&Hs[((size_t)tt * 16 + nin) * 512 + S * 32 + wave * 4],
          pk, __ATOMIC_RELAXED, __HIP_MEMORY_SCOPE_AGENT);
    }
    if (tt == T_ - 1) {
      hcf[nin * 512 + goff] = hn;
      hcf[B_ * H_ + nin * 512 + goff] = c_reg;
    }
    asm volatile("" ::: "memory");                   // store issued before next spin
    if (tt < T_ - 1) {                               // prefetch next G0 row;
      const float* gp = G0 + ((size_t)(tt + 1) * 16 + nin) * 2048 + goff;
      gx0 = gp[0]; gx1 = gp[512]; gx2 = gp[1024]; gx3 = gp[1536];
    }                                                // overlaps next data-spin
  }
}

// ---------------------------------------------------------------------------
extern "C" void kernel_launch(void* const* d_in, const int* in_sizes, int n_in,
                              void* d_out, int out_size, void* d_ws, size_t ws_size,
                              hipStream_t stream) {
  (void)in_sizes; (void)n_in; (void)out_size;
  const float* h0   = (const float*)d_in[1];
  const float* c0   = (const float*)d_in[2];
  const int*   tgt  = (const int*)d_in[3];
  const float* emb  = (const float*)d_in[4];
  const float* Wih  = (const float*)d_in[5];
  const float* Whh  = (const float*)d_in[6];
  const float* bih  = (const float*)d_in[7];
  const float* bhh  = (const float*)d_in[8];
  const float* Wout = (const float*)d_in[9];
  const float* bout = (const float*)d_in[10];
  float* out = (float*)d_out;

  char* ws = (char*)d_ws;
  short* wsWout = (short*)(ws);                 // 32,768,000 B
  short* wsWih  = (short*)(ws + 32768000);      //  2,097,152 B
  short* wsWhh  = (short*)(ws + 34865152);      //  2,097,152 B
  short* wsX    = (short*)(ws + 36962304);      //  2,097,152 B
  short* wsHs   = (short*)(ws + 39059456);      //  2,097,152 B
  const size_t NEED = 41160704ull + 16777216ull;
  // G0 in ws if it fits; else d_out scratch (safe: lstm_rec finishes reading
  // G0 before the logits gemm starts overwriting out — same stream).
  float* G0 = (ws_size >= NEED) ? (float*)(ws + 41160704) : out;

  cvt_bf16<<<16000, 256, 0, stream>>>(Wout, wsWout, 4096000);
  cvt_bf16<<<1024, 256, 0, stream>>>(Wih, wsWih, 262144);
  cvt_bf16<<<1024, 256, 0, stream>>>(Whh, wsWhh, 262144);
  gather_embed<<<2048, 128, 0, stream>>>(emb, tgt, wsX, wsHs);
  gemm_bt<<<dim3(16, 16), 256, 0, stream>>>(wsX, wsWih, bih, bhh, G0,
                                            2048, 2048, 512, 2048, 0);
  float* hcf = out + (size_t)B_ * T_ * V_;
  lstm_rec<<<16, 512, 0, stream>>>(G0, wsWhh, h0, c0, wsHs, hcf);
  gemm_bt<<<dim3(250, 16), 256, 0, stream>>>(wsHs, wsWout, bout, nullptr, out,
                                             2048, 32000, 512, 32000, 1);
}